// Round 24
// baseline (429.282 us; speedup 1.0000x reference)
//
#include <hip/hip_runtime.h>

// MixingAttention on MI355X (gfx950) — ROUND 24.
// r23 (128x256, BK32, 2 blocks/CU) = 427us best. This round: triple-buffer
// 2-ahead pipeline (depth-2 counted vmcnt: issue STAGE(i+2), wait vmcnt(6) ->
// tile i retired; tail vmcnt(3)/(0)). LDS 72KB, still 2 blocks/CU.
// Only the GEMM K-loop changes vs r23.

using s16x8 = __attribute__((ext_vector_type(8))) short;   // 8 bf16
using f32x4 = __attribute__((ext_vector_type(4))) float;   // 4 f32 acc
typedef __attribute__((ext_vector_type(2))) unsigned u32x2;

#define NTOK 144
#define NHEADS 16
#define CDIM 512
#define TROWS 9216
#define SROWS 36864
#define TOTROWS 46080
#define NWIN 320
#define NCLS 20

__device__ __forceinline__ unsigned short f2bf(float f) {
  unsigned u = __float_as_uint(f);
  u += 0x7fffu + ((u >> 16) & 1u);     // RNE
  return (unsigned short)(u >> 16);
}
__device__ __forceinline__ float bf2f(unsigned short u) {
  return __uint_as_float(((unsigned)u) << 16);
}
__device__ __forceinline__ s16x8 mk8(unsigned a, unsigned b, unsigned c, unsigned d) {
  union { unsigned u[4]; s16x8 v; } x;
  x.u[0] = a; x.u[1] = b; x.u[2] = c; x.u[3] = d;
  return x.v;
}

// async global->LDS, 16B per lane; lds base wave-uniform.
__device__ __forceinline__ void gld16(const void* g, void* l) {
  __builtin_amdgcn_global_load_lds(
      (const __attribute__((address_space(1))) unsigned int*)g,
      (__attribute__((address_space(3))) unsigned int*)l, 16, 0, 0);
}

// ---------------- prep kernels ----------------

__global__ void transpose_cast(const float* __restrict__ w,
                               unsigned short* __restrict__ wT, int Kd, int Nd,
                               int nScale, float s) {
  int i = blockIdx.x * 256 + threadIdx.x;
  if (i >= Kd * Nd) return;
  int n = i / Kd, k = i % Kd;
  float v = w[(size_t)k * Nd + n];
  if (n < nScale) v *= s;
  wT[i] = f2bf(v);
}

__global__ void scale_bias(const float* __restrict__ in, float* __restrict__ out) {
  int i = blockIdx.x * 256 + threadIdx.x;
  if (i >= 1536) return;
  out[i] = in[i] * (i < 512 ? 0.17677669529663687f : 1.0f);
}

__global__ __launch_bounds__(256) void cast_bf16(const float* __restrict__ in,
                                                 unsigned short* __restrict__ out, int n8) {
  int i = blockIdx.x * 256 + threadIdx.x;
  if (i >= n8) return;
  const float4* p = (const float4*)in + (size_t)i * 2;
  float4 f0 = p[0], f1 = p[1];
  s16x8 o;
  o[0] = (short)f2bf(f0.x); o[1] = (short)f2bf(f0.y);
  o[2] = (short)f2bf(f0.z); o[3] = (short)f2bf(f0.w);
  o[4] = (short)f2bf(f1.x); o[5] = (short)f2bf(f1.y);
  o[6] = (short)f2bf(f1.z); o[7] = (short)f2bf(f1.w);
  *(s16x8*)&out[(size_t)i * 8] = o;
}

__global__ void build_cmb(const float* __restrict__ rpb, const float* __restrict__ m0,
                          const float* __restrict__ m1, unsigned short* __restrict__ cmb) {
  int i = blockIdx.x * 256 + threadIdx.x;
  if (i >= NCLS * NHEADS * NTOK * NTOK) return;
  int cls = i / (NHEADS * NTOK * NTOK);
  int rem = i % (NHEADS * NTOK * NTOK);
  int h = rem / (NTOK * NTOK);
  int ij = rem % (NTOK * NTOK);
  int qi = ij / NTOK, kj = ij % NTOK;
  int dh = qi / 12 - kj / 12 + 11;
  int dw = qi % 12 - kj % 12 + 11;
  float bias = rpb[(dh * 23 + dw) * NHEADS + h];
  float mv = (cls < 4) ? m1[(size_t)cls * NTOK * NTOK + ij]
                       : m0[(size_t)(cls - 4) * NTOK * NTOK + ij];
  cmb[i] = f2bf(bias + mv);
}

// ---------------- 128x256 GEMM: BK=32, triple-buffer 2-ahead pipeline -------
// Wave (wr,wc): wr=wv>>2 rows [wr*64,+64), wc=wv&3 cols [wc*64,+64).
// LDS 72KB dynamic (shorts): A slot s at s*4096, B slot s at 12288 + s*8192.
// LDS (row, grp p of 4) holds global col-group p ^ (row&3).
// Steady state: STAGE(i+2) -> vmcnt(6) (tile i retired; newest 2 tiles in
// flight) -> barrier -> COMPUTE(i) -> barrier.  Tail: vmcnt(3)/vmcnt(0).
// EPI 0: +bias bf16.  EPI 1: +bias scatter [w][which][h][n][32].  EPI 2: f32.
template<int EPI>
__global__ __launch_bounds__(512, 4) void gemm128x256(
    const unsigned short* __restrict__ Ab,
    const unsigned short* __restrict__ BTt, const unsigned short* __restrict__ BTs,
    const float* __restrict__ biast, const float* __restrict__ biass,
    void* __restrict__ Cout, int gx, int nTiles, int M, int N, int K)
{
  extern __shared__ short smem[];          // 72KB
  const int t = threadIdx.x;
  const int lane = t & 63, wv = t >> 6, lg = lane >> 4, lc = lane & 15;
  const int wr = wv >> 2, wc = wv & 3;

  const int chunk = nTiles >> 3;
  const int sr = lane >> 2;
  const int scg = ((lane & 3) ^ ((lane >> 2) & 3)) * 8;
  const size_t rowK16 = (size_t)16 * K;
  const int T = K >> 5;                    // K-tiles (16 or 32)

  for (int tau = blockIdx.x; tau < nTiles; tau += gridDim.x) {
    const int lid = (tau & 7) * chunk + (tau >> 3);
    const int bn = (lid % gx) * 256, bm = (lid / gx) * 128;

    const bool isT = bm < TROWS;
    const unsigned short* BT = isT ? BTt : BTs;
    const float* bias = isT ? biast : biass;

    const unsigned short* aSrc = Ab + (size_t)(bm + wv * 16 + sr) * K + scg;
    const unsigned short* bSrc = BT + (size_t)(bn + wv * 32 + sr) * K + scg;

    f32x4 acc[4][4] = {};

    auto STAGE = [&](int sl, int kt) {
      short* Asb = smem + sl * 4096;
      short* Bsb = smem + 12288 + sl * 8192;
      gld16(aSrc + kt, Asb + wv * 512);
      gld16(bSrc + kt, Bsb + wv * 1024);
      gld16(bSrc + kt + rowK16, Bsb + wv * 1024 + 512);
    };
    auto COMPUTE = [&](int sl) {
      const short* Asb = smem + sl * 4096;
      const short* Bsb = smem + 12288 + sl * 8192;
      const int csw = 8 * (lg ^ (lc & 3));
      s16x8 bf[4];
#pragma unroll
      for (int c = 0; c < 4; c++)
        bf[c] = *(const s16x8*)&Bsb[(wc * 64 + c * 16 + lc) * 32 + csw];
#pragma unroll
      for (int r = 0; r < 4; r++) {
        s16x8 af = *(const s16x8*)&Asb[(wr * 64 + r * 16 + lc) * 32 + csw];
#pragma unroll
        for (int c = 0; c < 4; c++)
          acc[r][c] = __builtin_amdgcn_mfma_f32_16x16x32_bf16(af, bf[c], acc[r][c], 0, 0, 0);
      }
    };

    __builtin_amdgcn_s_barrier();   // prev tile's last COMPUTE reads done
    STAGE(0, 0);                     // slot 0 <- tile 0
    STAGE(1, 32);                    // slot 1 <- tile 1  (T >= 2 always)
    int sl = 0;
    for (int i = 0; i < T; i++) {
      if (i + 2 < T) {
        STAGE((sl + 2) % 3, (i + 2) * 32);          // 9 in flight
        asm volatile("s_waitcnt vmcnt(6)" ::: "memory");   // tile i retired
      } else if (i + 1 < T) {
        asm volatile("s_waitcnt vmcnt(3)" ::: "memory");   // only tile i+1 left
      } else {
        asm volatile("s_waitcnt vmcnt(0)" ::: "memory");
      }
      __builtin_amdgcn_s_barrier();
      __builtin_amdgcn_sched_barrier(0);
      COMPUTE(sl);
      __builtin_amdgcn_s_barrier();
      sl = (sl + 1) % 3;
    }

#pragma unroll
    for (int r = 0; r < 4; r++) {
      const int rbase = bm + wr * 64 + r * 16 + lg * 4;
#pragma unroll
      for (int c = 0; c < 4; c++) {
        const int cg = bn + wc * 64 + c * 16 + lc;
#pragma unroll
        for (int rr = 0; rr < 4; rr++) {
          const int rg = rbase + rr;
          float val = acc[r][c][rr] + bias[cg];
          if (EPI == 2) {
            ((float*)Cout)[(size_t)rg * N + cg] = val;
          } else if (EPI == 1) {
            const int wdw = rg / NTOK, n = rg % NTOK;
            const int which = cg >> 9, rem = cg & 511, hh = rem >> 5, dd = rem & 31;
            ((unsigned short*)Cout)[((((size_t)wdw * 3 + which) * NHEADS + hh) * NTOK + n) * 32 + dd]
                = f2bf(val);
          } else {
            ((unsigned short*)Cout)[(size_t)rg * N + cg] = f2bf(val);
          }
        }
      }
    }
  }
}

// ---------------- LayerNorm, in place (wave per row) ----------------
__global__ __launch_bounds__(256) void ln_kernel(
    unsigned short* __restrict__ xa,
    const float* __restrict__ g_pt, const float* __restrict__ be_pt,
    const float* __restrict__ g_ps, const float* __restrict__ be_ps)
{
  const int row = blockIdx.x * 4 + (threadIdx.x >> 6);
  const int lane = threadIdx.x & 63;
  const bool isT = row < TROWS;
  const float* gg = isT ? g_pt : g_ps;
  const float* be = isT ? be_pt : be_ps;
  unsigned short* p = xa + (size_t)row * CDIM;
  const int c0 = lane * 8;

  s16x8 v8 = *(const s16x8*)&p[c0];
  float f[8];
  float s = 0.f, s2 = 0.f;
#pragma unroll
  for (int i = 0; i < 8; i++) {
    float xv = bf2f((unsigned short)v8[i]);
    f[i] = xv; s += xv; s2 += xv * xv;
  }
#pragma unroll
  for (int d = 1; d < 64; d <<= 1) { s += __shfl_xor(s, d); s2 += __shfl_xor(s2, d); }
  float mu = s * (1.f / CDIM);
  float var = s2 * (1.f / CDIM) - mu * mu;
  float rs = rsqrtf(var + 1e-5f);

  float4 g0 = *(const float4*)&gg[c0], g1 = *(const float4*)&gg[c0 + 4];
  float4 e0 = *(const float4*)&be[c0], e1 = *(const float4*)&be[c0 + 4];
  float gv[8] = {g0.x, g0.y, g0.z, g0.w, g1.x, g1.y, g1.z, g1.w};
  float ev[8] = {e0.x, e0.y, e0.z, e0.w, e1.x, e1.y, e1.z, e1.w};
  s16x8 o;
#pragma unroll
  for (int i = 0; i < 8; i++)
    o[i] = (short)f2bf((f[i] - mu) * rs * gv[i] + ev[i]);
  *(s16x8*)&p[c0] = o;
}

// ---------------- fused attention, dense [w][which][h][n][32] reads --------
__global__ __launch_bounds__(576) void attn_kernel(
    const unsigned short* __restrict__ qkv, const unsigned short* __restrict__ cmb,
    unsigned short* __restrict__ outp)
{
  __shared__ short VT[32 * 168];
  const int nb = NWIN * NHEADS;
  const int lid = (blockIdx.x & 7) * (nb >> 3) + (blockIdx.x >> 3);
  const int w = lid >> 4, h = lid & 15;
  const int t = threadIdx.x;
  const unsigned short* qb = qkv + (size_t)w * 3 * NHEADS * NTOK * 32;
  const unsigned short* Qh = qb + (size_t)h * NTOK * 32;
  const unsigned short* Kh = qb + (size_t)(NHEADS + h) * NTOK * 32;
  const unsigned short* Vh = qb + (size_t)(2 * NHEADS + h) * NTOK * 32;

  {  // stage V transposed (dense 9KB panel)
    const int n = t >> 2, d0 = (t & 3) * 8;
    s16x8 vv = *(const s16x8*)&Vh[n * 32 + d0];
#pragma unroll
    for (int i = 0; i < 8; i++) VT[(d0 + i) * 168 + n] = vv[i];
  }
  if (t < 512) VT[(t >> 4) * 168 + 144 + (t & 15)] = 0;

  const int lane = t & 63, wv = t >> 6, lg = lane >> 4, lc = lane & 15;
  const int q = wv * 16 + lc;
  const f32x4 zero = {0.f, 0.f, 0.f, 0.f};

  const s16x8 qf = *(const s16x8*)&Qh[q * 32 + lg * 8];

  const int cls = (w < 64) ? (w & 3) : 4 + ((w - 64) & 15);
  const unsigned short* cm =
      cmb + ((size_t)cls * NHEADS + h) * (NTOK * NTOK) + (size_t)q * NTOK;
  uint2 cmr[9];
#pragma unroll
  for (int nt = 0; nt < 9; nt++)
    cmr[nt] = *(const uint2*)&cm[nt * 16 + lg * 4];

  f32x4 accS[9];
  __builtin_amdgcn_s_setprio(1);
#pragma unroll
  for (int nt = 0; nt < 9; nt++) {
    s16x8 kf = *(const s16x8*)&Kh[(nt * 16 + lc) * 32 + lg * 8];
    accS[nt] = __builtin_amdgcn_mfma_f32_16x16x32_bf16(kf, qf, zero, 0, 0, 0);
  }
  __builtin_amdgcn_s_setprio(0);

  float mx = -1e30f;
#pragma unroll
  for (int nt = 0; nt < 9; nt++) {
    accS[nt][0] += bf2f((unsigned short)(cmr[nt].x & 0xffff));
    accS[nt][1] += bf2f((unsigned short)(cmr[nt].x >> 16));
    accS[nt][2] += bf2f((unsigned short)(cmr[nt].y & 0xffff));
    accS[nt][3] += bf2f((unsigned short)(cmr[nt].y >> 16));
#pragma unroll
    for (int r = 0; r < 4; r++) mx = fmaxf(mx, accS[nt][r]);
  }
  mx = fmaxf(mx, __shfl_xor(mx, 16));
  mx = fmaxf(mx, __shfl_xor(mx, 32));

  float sum = 0.f;
#pragma unroll
  for (int nt = 0; nt < 9; nt++)
#pragma unroll
    for (int r = 0; r < 4; r++) {
      float e = __expf(accS[nt][r] - mx);
      accS[nt][r] = e;
      sum += e;
    }
  sum += __shfl_xor(sum, 16);
  sum += __shfl_xor(sum, 32);
  const float inv = 1.f / sum;

  unsigned pk0[9], pk1[9];
#pragma unroll
  for (int nt = 0; nt < 9; nt++) {
    pk0[nt] = (unsigned)f2bf(accS[nt][0]) | ((unsigned)f2bf(accS[nt][1]) << 16);
    pk1[nt] = (unsigned)f2bf(accS[nt][2]) | ((unsigned)f2bf(accS[nt][3]) << 16);
  }

  __syncthreads();

  __builtin_amdgcn_s_setprio(1);
#pragma unroll
  for (int dt = 0; dt < 2; dt++) {
    const short* vbase = &VT[(dt * 16 + lc) * 168];
    f32x4 accO = zero;
#pragma unroll
    for (int kk = 0; kk < 4; kk++) {
      u32x2 A0 = *(const u32x2*)&vbase[32 * kk + lg * 4];
      u32x2 A1 = *(const u32x2*)&vbase[32 * kk + 16 + lg * 4];
      s16x8 a = mk8(A0[0], A0[1], A1[0], A1[1]);
      s16x8 b = mk8(pk0[2 * kk], pk1[2 * kk], pk0[2 * kk + 1], pk1[2 * kk + 1]);
      accO = __builtin_amdgcn_mfma_f32_16x16x32_bf16(a, b, accO, 0, 0, 0);
    }
    {
      u32x2 A0 = *(const u32x2*)&vbase[128 + lg * 4];
      s16x8 a = mk8(A0[0], A0[1], 0u, 0u);
      s16x8 b = mk8(pk0[8], pk1[8], 0u, 0u);
      accO = __builtin_amdgcn_mfma_f32_16x16x32_bf16(a, b, accO, 0, 0, 0);
    }
    unsigned o0 = (unsigned)f2bf(accO[0] * inv) | ((unsigned)f2bf(accO[1] * inv) << 16);
    unsigned o1 = (unsigned)f2bf(accO[2] * inv) | ((unsigned)f2bf(accO[3] * inv) << 16);
    uint2 st; st.x = o0; st.y = o1;
    *(uint2*)&outp[(size_t)(w * NTOK + q) * CDIM + h * 32 + dt * 16 + lg * 4] = st;
  }
  __builtin_amdgcn_s_setprio(0);
}

// ---------------- launch ----------------
extern "C" void kernel_launch(void* const* d_in, const int* in_sizes, int n_in,
                              void* d_out, int out_size, void* d_ws, size_t ws_size,
                              hipStream_t stream)
{
  const float* x     = (const float*)d_in[0];
  const float* tpl   = (const float*)d_in[1];
  const float* mask0 = (const float*)d_in[2];
  const float* mask1 = (const float*)d_in[3];
  const float* rpb   = (const float*)d_in[8];
  const float* w_ps  = (const float*)d_in[9];
  const float* b_ps  = (const float*)d_in[10];
  const float* g_ps  = (const float*)d_in[11];
  const float* be_ps = (const float*)d_in[12];
  const float* w_pt  = (const float*)d_in[13];
  const float* b_pt  = (const float*)d_in[14];
  const float* g_pt  = (const float*)d_in[15];
  const float* be_pt = (const float*)d_in[16];
  const float* w_qkv = (const float*)d_in[17];
  const float* b_qkv = (const float*)d_in[18];
  const float* w_tr  = (const float*)d_in[19];
  const float* b_tr  = (const float*)d_in[20];
  const float* w_sr  = (const float*)d_in[21];
  const float* b_sr  = (const float*)d_in[22];

  char* ws = (char*)d_ws;
  unsigned short* wpsT  = (unsigned short*)(ws + 0x0000000);
  unsigned short* wptT  = (unsigned short*)(ws + 0x0100000);
  unsigned short* wqkvT = (unsigned short*)(ws + 0x0200000);
  unsigned short* wtrT  = (unsigned short*)(ws + 0x0380000);
  unsigned short* wsrT  = (unsigned short*)(ws + 0x0480000);
  unsigned short* cmb   = (unsigned short*)(ws + 0x0580000);
  float* bqS            = (float*)(ws + 0x12F0000);
  unsigned short* xa    = (unsigned short*)(ws + 0x1300000);
  unsigned short* Sa    = (unsigned short*)(ws + 0x4000000);   // cast-A (union w/ qkv)
  unsigned short* qkvF  = (unsigned short*)(ws + 0x4000000);
  float* outb           = (float*)d_out;

  hipFuncSetAttribute((const void*)gemm128x256<0>,
                      hipFuncAttributeMaxDynamicSharedMemorySize, 73728);
  hipFuncSetAttribute((const void*)gemm128x256<1>,
                      hipFuncAttributeMaxDynamicSharedMemorySize, 73728);
  hipFuncSetAttribute((const void*)gemm128x256<2>,
                      hipFuncAttributeMaxDynamicSharedMemorySize, 73728);

  transpose_cast<<<2048, 256, 0, stream>>>(w_ps, wpsT, 1024, 512, 0, 1.f);
  transpose_cast<<<2048, 256, 0, stream>>>(w_pt, wptT, 1024, 512, 0, 1.f);
  transpose_cast<<<3072, 256, 0, stream>>>(w_qkv, wqkvT, 512, 1536,
                                           512, 0.17677669529663687f);
  transpose_cast<<<2048, 256, 0, stream>>>(w_tr, wtrT, 512, 1024, 0, 1.f);
  transpose_cast<<<2048, 256, 0, stream>>>(w_sr, wsrT, 512, 1024, 0, 1.f);
  scale_bias<<<6, 256, 0, stream>>>(b_qkv, bqS);
  build_cmb<<<(NCLS * NHEADS * NTOK * NTOK + 255) / 256, 256, 0, stream>>>(rpb, mask0, mask1, cmb);

  // cast inputs to bf16: tpl -> Sa[0:9216), x -> Sa[9216:46080)
  cast_bf16<<<(TROWS * 1024 / 8 + 255) / 256, 256, 0, stream>>>(tpl, Sa, TROWS * 1024 / 8);
  cast_bf16<<<(SROWS * 1024 / 8 + 255) / 256, 256, 0, stream>>>(
      x, Sa + (size_t)TROWS * 1024, SROWS * 1024 / 8);

  // projection GEMM -> xa bf16 (720 tiles)
  gemm128x256<0><<<512, 512, 73728, stream>>>(Sa, wptT, wpsT, b_pt, b_ps,
                                              xa, 2, 720, TOTROWS, CDIM, 1024);
  // LayerNorm in place on xa
  ln_kernel<<<TOTROWS / 4, 256, 0, stream>>>(xa, g_pt, be_pt, g_ps, be_ps);

  // QKV GEMM (Q-scale folded) -> qkvF in attention layout (2160 tiles)
  gemm128x256<1><<<512, 512, 73728, stream>>>(xa, wqkvT, wqkvT, bqS, bqS,
                                              qkvF, 6, 2160, TOTROWS, 1536, CDIM);
  // fused attention -> xa
  attn_kernel<<<NWIN * NHEADS, 576, 0, stream>>>(qkvF, cmb, xa);

  // output GEMM -> d_out f32 (1440 tiles)
  gemm128x256<2><<<512, 512, 73728, stream>>>(xa, wtrT, wsrT, b_tr, b_sr,
                                              outb, 4, 1440, TOTROWS, 1024, CDIM);
}

// Round 25
// 423.228 us; speedup vs baseline: 1.0143x; 1.0143x over previous
//
#include <hip/hip_runtime.h>

// MixingAttention on MI355X (gfx950) — ROUND 25.
// r24 (triple-buffer) neutral -> reverted to r23 dbuf GEMM (427us best).
// New: attention block order grouped by (cls,h) — the 16 windows sharing a
// 41.5KB cmb bias+mask panel now run back-to-back on one XCD (panel hits L2
// 15/16 times). Removes ~200MB of avoidable HBM traffic from attention.

using s16x8 = __attribute__((ext_vector_type(8))) short;   // 8 bf16
using f32x4 = __attribute__((ext_vector_type(4))) float;   // 4 f32 acc
typedef __attribute__((ext_vector_type(2))) unsigned u32x2;

#define NTOK 144
#define NHEADS 16
#define CDIM 512
#define TROWS 9216
#define SROWS 36864
#define TOTROWS 46080
#define NWIN 320
#define NCLS 20

__device__ __forceinline__ unsigned short f2bf(float f) {
  unsigned u = __float_as_uint(f);
  u += 0x7fffu + ((u >> 16) & 1u);     // RNE
  return (unsigned short)(u >> 16);
}
__device__ __forceinline__ float bf2f(unsigned short u) {
  return __uint_as_float(((unsigned)u) << 16);
}
__device__ __forceinline__ s16x8 mk8(unsigned a, unsigned b, unsigned c, unsigned d) {
  union { unsigned u[4]; s16x8 v; } x;
  x.u[0] = a; x.u[1] = b; x.u[2] = c; x.u[3] = d;
  return x.v;
}

// async global->LDS, 16B per lane; lds base wave-uniform.
__device__ __forceinline__ void gld16(const void* g, void* l) {
  __builtin_amdgcn_global_load_lds(
      (const __attribute__((address_space(1))) unsigned int*)g,
      (__attribute__((address_space(3))) unsigned int*)l, 16, 0, 0);
}

// ---------------- prep kernels ----------------

__global__ void transpose_cast(const float* __restrict__ w,
                               unsigned short* __restrict__ wT, int Kd, int Nd,
                               int nScale, float s) {
  int i = blockIdx.x * 256 + threadIdx.x;
  if (i >= Kd * Nd) return;
  int n = i / Kd, k = i % Kd;
  float v = w[(size_t)k * Nd + n];
  if (n < nScale) v *= s;
  wT[i] = f2bf(v);
}

__global__ void scale_bias(const float* __restrict__ in, float* __restrict__ out) {
  int i = blockIdx.x * 256 + threadIdx.x;
  if (i >= 1536) return;
  out[i] = in[i] * (i < 512 ? 0.17677669529663687f : 1.0f);
}

__global__ __launch_bounds__(256) void cast_bf16(const float* __restrict__ in,
                                                 unsigned short* __restrict__ out, int n8) {
  int i = blockIdx.x * 256 + threadIdx.x;
  if (i >= n8) return;
  const float4* p = (const float4*)in + (size_t)i * 2;
  float4 f0 = p[0], f1 = p[1];
  s16x8 o;
  o[0] = (short)f2bf(f0.x); o[1] = (short)f2bf(f0.y);
  o[2] = (short)f2bf(f0.z); o[3] = (short)f2bf(f0.w);
  o[4] = (short)f2bf(f1.x); o[5] = (short)f2bf(f1.y);
  o[6] = (short)f2bf(f1.z); o[7] = (short)f2bf(f1.w);
  *(s16x8*)&out[(size_t)i * 8] = o;
}

__global__ void build_cmb(const float* __restrict__ rpb, const float* __restrict__ m0,
                          const float* __restrict__ m1, unsigned short* __restrict__ cmb) {
  int i = blockIdx.x * 256 + threadIdx.x;
  if (i >= NCLS * NHEADS * NTOK * NTOK) return;
  int cls = i / (NHEADS * NTOK * NTOK);
  int rem = i % (NHEADS * NTOK * NTOK);
  int h = rem / (NTOK * NTOK);
  int ij = rem % (NTOK * NTOK);
  int qi = ij / NTOK, kj = ij % NTOK;
  int dh = qi / 12 - kj / 12 + 11;
  int dw = qi % 12 - kj % 12 + 11;
  float bias = rpb[(dh * 23 + dw) * NHEADS + h];
  float mv = (cls < 4) ? m1[(size_t)cls * NTOK * NTOK + ij]
                       : m0[(size_t)(cls - 4) * NTOK * NTOK + ij];
  cmb[i] = f2bf(bias + mv);
}

// ---------------- 128x256 GEMM: BK=32, dbuf, 2 blocks/CU (r23) ----------
template<int EPI>
__global__ __launch_bounds__(512, 4) void gemm128x256(
    const unsigned short* __restrict__ Ab,
    const unsigned short* __restrict__ BTt, const unsigned short* __restrict__ BTs,
    const float* __restrict__ biast, const float* __restrict__ biass,
    void* __restrict__ Cout, int gx, int nTiles, int M, int N, int K)
{
  extern __shared__ short smem[];          // 48KB
  const int t = threadIdx.x;
  const int lane = t & 63, wv = t >> 6, lg = lane >> 4, lc = lane & 15;
  const int wr = wv >> 2, wc = wv & 3;

  const int chunk = nTiles >> 3;
  const int sr = lane >> 2;
  const int scg = ((lane & 3) ^ ((lane >> 2) & 3)) * 8;
  const size_t rowK16 = (size_t)16 * K;

  for (int tau = blockIdx.x; tau < nTiles; tau += gridDim.x) {
    const int lid = (tau & 7) * chunk + (tau >> 3);
    const int bn = (lid % gx) * 256, bm = (lid / gx) * 128;

    const bool isT = bm < TROWS;
    const unsigned short* BT = isT ? BTt : BTs;
    const float* bias = isT ? biast : biass;

    const unsigned short* aSrc = Ab + (size_t)(bm + wv * 16 + sr) * K + scg;
    const unsigned short* bSrc = BT + (size_t)(bn + wv * 32 + sr) * K + scg;

    f32x4 acc[4][4] = {};

    auto STAGE = [&](int b, int kt) {
      short* Asb = smem + b * 4096;
      short* Bsb = smem + 8192 + b * 8192;
      gld16(aSrc + kt, Asb + wv * 512);
      gld16(bSrc + kt, Bsb + wv * 1024);
      gld16(bSrc + kt + rowK16, Bsb + wv * 1024 + 512);
    };
    auto COMPUTE = [&](int b) {
      const short* Asb = smem + b * 4096;
      const short* Bsb = smem + 8192 + b * 8192;
      const int csw = 8 * (lg ^ (lc & 3));
      s16x8 bf[4];
#pragma unroll
      for (int c = 0; c < 4; c++)
        bf[c] = *(const s16x8*)&Bsb[(wc * 64 + c * 16 + lc) * 32 + csw];
#pragma unroll
      for (int r = 0; r < 4; r++) {
        s16x8 af = *(const s16x8*)&Asb[(wr * 64 + r * 16 + lc) * 32 + csw];
#pragma unroll
        for (int c = 0; c < 4; c++)
          acc[r][c] = __builtin_amdgcn_mfma_f32_16x16x32_bf16(af, bf[c], acc[r][c], 0, 0, 0);
      }
    };

    __builtin_amdgcn_s_barrier();   // prev tile's last COMPUTE reads done
    STAGE(0, 0);
    int cur = 0;
    for (int kt = 32; kt < K; kt += 32) {
      STAGE(cur ^ 1, kt);
      asm volatile("s_waitcnt vmcnt(3)" ::: "memory");
      __builtin_amdgcn_s_barrier();
      __builtin_amdgcn_sched_barrier(0);
      COMPUTE(cur);
      __builtin_amdgcn_s_barrier();
      cur ^= 1;
    }
    asm volatile("s_waitcnt vmcnt(0)" ::: "memory");
    __builtin_amdgcn_s_barrier();
    __builtin_amdgcn_sched_barrier(0);
    COMPUTE(cur);

#pragma unroll
    for (int r = 0; r < 4; r++) {
      const int rbase = bm + wr * 64 + r * 16 + lg * 4;
#pragma unroll
      for (int c = 0; c < 4; c++) {
        const int cg = bn + wc * 64 + c * 16 + lc;
#pragma unroll
        for (int rr = 0; rr < 4; rr++) {
          const int rg = rbase + rr;
          float val = acc[r][c][rr] + bias[cg];
          if (EPI == 2) {
            ((float*)Cout)[(size_t)rg * N + cg] = val;
          } else if (EPI == 1) {
            const int wdw = rg / NTOK, n = rg % NTOK;
            const int which = cg >> 9, rem = cg & 511, hh = rem >> 5, dd = rem & 31;
            ((unsigned short*)Cout)[((((size_t)wdw * 3 + which) * NHEADS + hh) * NTOK + n) * 32 + dd]
                = f2bf(val);
          } else {
            ((unsigned short*)Cout)[(size_t)rg * N + cg] = f2bf(val);
          }
        }
      }
    }
  }
}

// ---------------- LayerNorm, in place (wave per row) ----------------
__global__ __launch_bounds__(256) void ln_kernel(
    unsigned short* __restrict__ xa,
    const float* __restrict__ g_pt, const float* __restrict__ be_pt,
    const float* __restrict__ g_ps, const float* __restrict__ be_ps)
{
  const int row = blockIdx.x * 4 + (threadIdx.x >> 6);
  const int lane = threadIdx.x & 63;
  const bool isT = row < TROWS;
  const float* gg = isT ? g_pt : g_ps;
  const float* be = isT ? be_pt : be_ps;
  unsigned short* p = xa + (size_t)row * CDIM;
  const int c0 = lane * 8;

  s16x8 v8 = *(const s16x8*)&p[c0];
  float f[8];
  float s = 0.f, s2 = 0.f;
#pragma unroll
  for (int i = 0; i < 8; i++) {
    float xv = bf2f((unsigned short)v8[i]);
    f[i] = xv; s += xv; s2 += xv * xv;
  }
#pragma unroll
  for (int d = 1; d < 64; d <<= 1) { s += __shfl_xor(s, d); s2 += __shfl_xor(s2, d); }
  float mu = s * (1.f / CDIM);
  float var = s2 * (1.f / CDIM) - mu * mu;
  float rs = rsqrtf(var + 1e-5f);

  float4 g0 = *(const float4*)&gg[c0], g1 = *(const float4*)&gg[c0 + 4];
  float4 e0 = *(const float4*)&be[c0], e1 = *(const float4*)&be[c0 + 4];
  float gv[8] = {g0.x, g0.y, g0.z, g0.w, g1.x, g1.y, g1.z, g1.w};
  float ev[8] = {e0.x, e0.y, e0.z, e0.w, e1.x, e1.y, e1.z, e1.w};
  s16x8 o;
#pragma unroll
  for (int i = 0; i < 8; i++)
    o[i] = (short)f2bf((f[i] - mu) * rs * gv[i] + ev[i]);
  *(s16x8*)&p[c0] = o;
}

// ---------------- fused attention, (cls,h)-grouped block order --------------
// lid = chunked-XCD(blockIdx); gid = lid>>4 (group), widx = lid&15.
// gid<64: template — cls=gid>>4, h=gid&15, w=cls+4*widx.
// gid>=64: search  — s=(gid-64)>>4, cls=4+s, h=gid&15, w=64+s+16*widx.
// The 16 blocks of a group share one 41.5KB cmb panel, run consecutively
// on one XCD -> panel L2-resident (HBM read once per group).
__global__ __launch_bounds__(576) void attn_kernel(
    const unsigned short* __restrict__ qkv, const unsigned short* __restrict__ cmb,
    unsigned short* __restrict__ outp)
{
  __shared__ short VT[32 * 168];
  const int lid = (blockIdx.x & 7) * ((NWIN * NHEADS) >> 3) + (blockIdx.x >> 3);
  const int gid = lid >> 4, widx = lid & 15;
  int w, cls;
  if (gid < 64) { cls = gid >> 4; w = cls + 4 * widx; }
  else { int s = (gid - 64) >> 4; cls = 4 + s; w = 64 + s + 16 * widx; }
  const int h = gid & 15;

  const int t = threadIdx.x;
  const unsigned short* qb = qkv + (size_t)w * 3 * NHEADS * NTOK * 32;
  const unsigned short* Qh = qb + (size_t)h * NTOK * 32;
  const unsigned short* Kh = qb + (size_t)(NHEADS + h) * NTOK * 32;
  const unsigned short* Vh = qb + (size_t)(2 * NHEADS + h) * NTOK * 32;

  {  // stage V transposed (dense 9KB panel)
    const int n = t >> 2, d0 = (t & 3) * 8;
    s16x8 vv = *(const s16x8*)&Vh[n * 32 + d0];
#pragma unroll
    for (int i = 0; i < 8; i++) VT[(d0 + i) * 168 + n] = vv[i];
  }
  if (t < 512) VT[(t >> 4) * 168 + 144 + (t & 15)] = 0;

  const int lane = t & 63, wv = t >> 6, lg = lane >> 4, lc = lane & 15;
  const int q = wv * 16 + lc;
  const f32x4 zero = {0.f, 0.f, 0.f, 0.f};

  const s16x8 qf = *(const s16x8*)&Qh[q * 32 + lg * 8];

  const unsigned short* cm =
      cmb + ((size_t)cls * NHEADS + h) * (NTOK * NTOK) + (size_t)q * NTOK;
  uint2 cmr[9];
#pragma unroll
  for (int nt = 0; nt < 9; nt++)
    cmr[nt] = *(const uint2*)&cm[nt * 16 + lg * 4];

  f32x4 accS[9];
  __builtin_amdgcn_s_setprio(1);
#pragma unroll
  for (int nt = 0; nt < 9; nt++) {
    s16x8 kf = *(const s16x8*)&Kh[(nt * 16 + lc) * 32 + lg * 8];
    accS[nt] = __builtin_amdgcn_mfma_f32_16x16x32_bf16(kf, qf, zero, 0, 0, 0);
  }
  __builtin_amdgcn_s_setprio(0);

  float mx = -1e30f;
#pragma unroll
  for (int nt = 0; nt < 9; nt++) {
    accS[nt][0] += bf2f((unsigned short)(cmr[nt].x & 0xffff));
    accS[nt][1] += bf2f((unsigned short)(cmr[nt].x >> 16));
    accS[nt][2] += bf2f((unsigned short)(cmr[nt].y & 0xffff));
    accS[nt][3] += bf2f((unsigned short)(cmr[nt].y >> 16));
#pragma unroll
    for (int r = 0; r < 4; r++) mx = fmaxf(mx, accS[nt][r]);
  }
  mx = fmaxf(mx, __shfl_xor(mx, 16));
  mx = fmaxf(mx, __shfl_xor(mx, 32));

  float sum = 0.f;
#pragma unroll
  for (int nt = 0; nt < 9; nt++)
#pragma unroll
    for (int r = 0; r < 4; r++) {
      float e = __expf(accS[nt][r] - mx);
      accS[nt][r] = e;
      sum += e;
    }
  sum += __shfl_xor(sum, 16);
  sum += __shfl_xor(sum, 32);
  const float inv = 1.f / sum;

  unsigned pk0[9], pk1[9];
#pragma unroll
  for (int nt = 0; nt < 9; nt++) {
    pk0[nt] = (unsigned)f2bf(accS[nt][0]) | ((unsigned)f2bf(accS[nt][1]) << 16);
    pk1[nt] = (unsigned)f2bf(accS[nt][2]) | ((unsigned)f2bf(accS[nt][3]) << 16);
  }

  __syncthreads();

  __builtin_amdgcn_s_setprio(1);
#pragma unroll
  for (int dt = 0; dt < 2; dt++) {
    const short* vbase = &VT[(dt * 16 + lc) * 168];
    f32x4 accO = zero;
#pragma unroll
    for (int kk = 0; kk < 4; kk++) {
      u32x2 A0 = *(const u32x2*)&vbase[32 * kk + lg * 4];
      u32x2 A1 = *(const u32x2*)&vbase[32 * kk + 16 + lg * 4];
      s16x8 a = mk8(A0[0], A0[1], A1[0], A1[1]);
      s16x8 b = mk8(pk0[2 * kk], pk1[2 * kk], pk0[2 * kk + 1], pk1[2 * kk + 1]);
      accO = __builtin_amdgcn_mfma_f32_16x16x32_bf16(a, b, accO, 0, 0, 0);
    }
    {
      u32x2 A0 = *(const u32x2*)&vbase[128 + lg * 4];
      s16x8 a = mk8(A0[0], A0[1], 0u, 0u);
      s16x8 b = mk8(pk0[8], pk1[8], 0u, 0u);
      accO = __builtin_amdgcn_mfma_f32_16x16x32_bf16(a, b, accO, 0, 0, 0);
    }
    unsigned o0 = (unsigned)f2bf(accO[0] * inv) | ((unsigned)f2bf(accO[1] * inv) << 16);
    unsigned o1 = (unsigned)f2bf(accO[2] * inv) | ((unsigned)f2bf(accO[3] * inv) << 16);
    uint2 st; st.x = o0; st.y = o1;
    *(uint2*)&outp[(size_t)(w * NTOK + q) * CDIM + h * 32 + dt * 16 + lg * 4] = st;
  }
  __builtin_amdgcn_s_setprio(0);
}

// ---------------- launch ----------------
extern "C" void kernel_launch(void* const* d_in, const int* in_sizes, int n_in,
                              void* d_out, int out_size, void* d_ws, size_t ws_size,
                              hipStream_t stream)
{
  const float* x     = (const float*)d_in[0];
  const float* tpl   = (const float*)d_in[1];
  const float* mask0 = (const float*)d_in[2];
  const float* mask1 = (const float*)d_in[3];
  const float* rpb   = (const float*)d_in[8];
  const float* w_ps  = (const float*)d_in[9];
  const float* b_ps  = (const float*)d_in[10];
  const float* g_ps  = (const float*)d_in[11];
  const float* be_ps = (const float*)d_in[12];
  const float* w_pt  = (const float*)d_in[13];
  const float* b_pt  = (const float*)d_in[14];
  const float* g_pt  = (const float*)d_in[15];
  const float* be_pt = (const float*)d_in[16];
  const float* w_qkv = (const float*)d_in[17];
  const float* b_qkv = (const float*)d_in[18];
  const float* w_tr  = (const float*)d_in[19];
  const float* b_tr  = (const float*)d_in[20];
  const float* w_sr  = (const float*)d_in[21];
  const float* b_sr  = (const float*)d_in[22];

  char* ws = (char*)d_ws;
  unsigned short* wpsT  = (unsigned short*)(ws + 0x0000000);
  unsigned short* wptT  = (unsigned short*)(ws + 0x0100000);
  unsigned short* wqkvT = (unsigned short*)(ws + 0x0200000);
  unsigned short* wtrT  = (unsigned short*)(ws + 0x0380000);
  unsigned short* wsrT  = (unsigned short*)(ws + 0x0480000);
  unsigned short* cmb   = (unsigned short*)(ws + 0x0580000);
  float* bqS            = (float*)(ws + 0x12F0000);
  unsigned short* xa    = (unsigned short*)(ws + 0x1300000);
  unsigned short* Sa    = (unsigned short*)(ws + 0x4000000);   // cast-A (union w/ qkv)
  unsigned short* qkvF  = (unsigned short*)(ws + 0x4000000);
  float* outb           = (float*)d_out;

  hipFuncSetAttribute((const void*)gemm128x256<0>,
                      hipFuncAttributeMaxDynamicSharedMemorySize, 49152);
  hipFuncSetAttribute((const void*)gemm128x256<1>,
                      hipFuncAttributeMaxDynamicSharedMemorySize, 49152);
  hipFuncSetAttribute((const void*)gemm128x256<2>,
                      hipFuncAttributeMaxDynamicSharedMemorySize, 49152);

  transpose_cast<<<2048, 256, 0, stream>>>(w_ps, wpsT, 1024, 512, 0, 1.f);
  transpose_cast<<<2048, 256, 0, stream>>>(w_pt, wptT, 1024, 512, 0, 1.f);
  transpose_cast<<<3072, 256, 0, stream>>>(w_qkv, wqkvT, 512, 1536,
                                           512, 0.17677669529663687f);
  transpose_cast<<<2048, 256, 0, stream>>>(w_tr, wtrT, 512, 1024, 0, 1.f);
  transpose_cast<<<2048, 256, 0, stream>>>(w_sr, wsrT, 512, 1024, 0, 1.f);
  scale_bias<<<6, 256, 0, stream>>>(b_qkv, bqS);
  build_cmb<<<(NCLS * NHEADS * NTOK * NTOK + 255) / 256, 256, 0, stream>>>(rpb, mask0, mask1, cmb);

  // cast inputs to bf16: tpl -> Sa[0:9216), x -> Sa[9216:46080)
  cast_bf16<<<(TROWS * 1024 / 8 + 255) / 256, 256, 0, stream>>>(tpl, Sa, TROWS * 1024 / 8);
  cast_bf16<<<(SROWS * 1024 / 8 + 255) / 256, 256, 0, stream>>>(
      x, Sa + (size_t)TROWS * 1024, SROWS * 1024 / 8);

  // projection GEMM -> xa bf16 (720 tiles)
  gemm128x256<0><<<512, 512, 49152, stream>>>(Sa, wptT, wpsT, b_pt, b_ps,
                                              xa, 2, 720, TOTROWS, CDIM, 1024);
  // LayerNorm in place on xa
  ln_kernel<<<TOTROWS / 4, 256, 0, stream>>>(xa, g_pt, be_pt, g_ps, be_ps);

  // QKV GEMM (Q-scale folded) -> qkvF in attention layout (2160 tiles)
  gemm128x256<1><<<512, 512, 49152, stream>>>(xa, wqkvT, wqkvT, bqS, bqS,
                                              qkvF, 6, 2160, TOTROWS, 1536, CDIM);
  // fused attention -> xa
  attn_kernel<<<NWIN * NHEADS, 576, 0, stream>>>(qkvF, cmb, xa);

  // output GEMM -> d_out f32 (1440 tiles)
  gemm128x256<2><<<512, 512, 49152, stream>>>(xa, wtrT, wsrT, b_tr, b_sr,
                                              outb, 4, 1440, TOTROWS, 1024, CDIM);
}